// Round 1
// baseline (1715.017 us; speedup 1.0000x reference)
//
#include <hip/hip_runtime.h>
#include <hip/hip_bf16.h>

#define N_NODES 10000
#define N_EDGES 160000

__device__ __forceinline__ float sigf(float x){ return 1.0f/(1.0f+__expf(-x)); }
__device__ __forceinline__ float siluf(float x){ return x*sigf(x); }

__device__ __forceinline__ unsigned int f2bfbits(float f){
  unsigned int u = __float_as_uint(f);
  return (u + 0x7fffu + ((u>>16)&1u)) >> 16;
}
__device__ __forceinline__ unsigned int bfp(float a, float b){
  return f2bfbits(a) | (f2bfbits(b)<<16);
}
__device__ __forceinline__ float bflo(unsigned int u){ return __uint_as_float(u<<16); }
__device__ __forceinline__ float bfhi(unsigned int u){ return __uint_as_float(u & 0xffff0000u); }

// ---------------- pack/permute weights ----------------
// wr4p[k][c][q] = Wr4[k][q*128+c] * (1/sqrt(64))    (64x512)
// d' layout: d' = c*8 + slot, slot: 0=m1(u=c) 1=m4(u=128+c) 2..4=m2(u=c,m) 5..7=m3(u=128+c,m)
// wse1p[d'][j] = W_se1[d(d')][j]                    (1024x32)
// wse2p[j][d'] = W_se2[j][d(d')]                    (32x1024)
__global__ void pack_weights(const float* __restrict__ Wr4,
                             const float* __restrict__ Wse1,
                             const float* __restrict__ Wse2,
                             float* __restrict__ wr4p,
                             float* __restrict__ wse1p,
                             float* __restrict__ wse2p)
{
  int t = blockIdx.x*256 + threadIdx.x;   // 0..32767
  {
    int k = t >> 9; int rem = t & 511; int c = rem >> 2; int q = rem & 3;
    wr4p[t] = Wr4[k*512 + q*128 + c] * 0.125f;
  }
  {
    int dp = t >> 5; int j = t & 31;
    int c = dp >> 3; int slot = dp & 7;
    int d;
    if (slot==0) d = c;
    else if (slot==1) d = 128 + c;
    else if (slot<5) d = 256 + 3*c + (slot-2);
    else d = 640 + 3*c + (slot-5);
    wse1p[dp*32 + j] = Wse1[d*32 + j];
    wse2p[j*1024 + dp] = Wse2[j*1024 + d];
  }
}

// ---------------- node up-projection ----------------
__global__ __launch_bounds__(128) void node_up_kernel(
    const float* __restrict__ nf, const float* __restrict__ W0, const float* __restrict__ W1,
    float* __restrict__ s_up, float* __restrict__ v_up)
{
  int n = blockIdx.x; int c = threadIdx.x;
  __shared__ float row[512];
  #pragma unroll
  for (int i=0;i<4;i++) row[c + 128*i] = nf[n*512 + c + 128*i];
  __syncthreads();
  float as=0.f, a0=0.f, a1=0.f, a2=0.f;
  for (int u=0;u<128;u++){
    float w0 = W0[u*128+c], w1 = W1[u*128+c];
    as += row[u]*w0;
    a0 += row[128+u*3+0]*w1;
    a1 += row[128+u*3+1]*w1;
    a2 += row[128+u*3+2]*w1;
  }
  const float f = 0.08838834764831845f;   // 1/sqrt(128)
  s_up[n*128+c] = as*f;
  v_up[n*384 + c*3+0] = a0*f;
  v_up[n*384 + c*3+1] = a1*f;
  v_up[n*384 + c*3+2] = a2*f;
}

// ---------------- fused edge kernel (16 edges / block) ----------------
__global__ __launch_bounds__(512, 4) void edge_kernel(
    const float* __restrict__ ef, const float* __restrict__ ea, const int* __restrict__ ei,
    const float* __restrict__ Wr1, const float* __restrict__ Wr2, const float* __restrict__ Wr3,
    const float* __restrict__ wr4p, const float* __restrict__ wse1p, const float* __restrict__ wse2p,
    const float* __restrict__ s_up, const float* __restrict__ v_up, float* __restrict__ acc)
{
  __shared__ __align__(16) float hA[16*64];
  __shared__ __align__(16) float hB[16*64];
  __shared__ uint4 mjit[16*128];          // bf16 x8 per (e,c)
  __shared__ float sg1[16*32];
  __shared__ int s_src[16], s_dst[16];
  __shared__ float s_y[16][4];
  const int t = threadIdx.x;
  const int e0 = blockIdx.x * 16;

  if (t < 16){ s_src[t] = ei[e0+t]; s_dst[t] = ei[N_EDGES + e0 + t]; }
  else if (t >= 64 && t < 128){ int q=t-64; s_y[q>>2][q&3] = ea[(e0+(q>>2))*4 + (q&3)]; }

  // ---- P1: MLP 8->64->64->64 (+silu). thread=(unit i, edge eh & eh+8) ----
  {
    const int i = t & 63, eh = t >> 6;
    float r0, r1;
    { float a0=0.f,a1=0.f;
      #pragma unroll
      for (int k=0;k<8;k++){ float w = Wr1[k*64+i];
        a0 += ef[(e0+eh)*8+k]*w; a1 += ef[(e0+eh+8)*8+k]*w; }
      r0 = siluf(a0*0.35355339059327373f); r1 = siluf(a1*0.35355339059327373f);
    }
    hA[eh*64+i]=r0; hA[(eh+8)*64+i]=r1;
    __syncthreads();
    { float a0=0.f,a1=0.f;
      for (int k=0;k<64;k++){ float w = Wr2[k*64+i];
        a0 += hA[eh*64+k]*w; a1 += hA[(eh+8)*64+k]*w; }
      r0=siluf(a0*0.125f); r1=siluf(a1*0.125f);
    }
    hB[eh*64+i]=r0; hB[(eh+8)*64+i]=r1;
    __syncthreads();
    { float a0=0.f,a1=0.f;
      for (int k=0;k<64;k++){ float w = Wr3[k*64+i];
        a0 += hB[eh*64+k]*w; a1 += hB[(eh+8)*64+k]*w; }
      r0=siluf(a0*0.125f); r1=siluf(a1*0.125f);
    }
    hA[eh*64+i]=r0; hA[(eh+8)*64+i]=r1;   // h3 -> hA (nobody reads hA after 2nd sync)
  }
  __syncthreads();

  // ---- P2: tpw + gather + messages -> mji tile (bf16) ----
  {
    const int c = t & 127, es = t >> 7;
    float tp[4][4];
    #pragma unroll
    for (int ii=0;ii<4;ii++){ tp[ii][0]=0.f; tp[ii][1]=0.f; tp[ii][2]=0.f; tp[ii][3]=0.f; }
    for (int k=0;k<64;k++){
      float4 w = *(const float4*)(wr4p + k*512 + c*4);
      #pragma unroll
      for (int ii=0;ii<4;ii++){
        float h = hA[(es+4*ii)*64+k];
        tp[ii][0] += h*w.x; tp[ii][1] += h*w.y; tp[ii][2] += h*w.z; tp[ii][3] += h*w.w;
      }
    }
    #pragma unroll
    for (int ii=0;ii<4;ii++){
      int e = es + 4*ii;
      int src = s_src[e];
      float y0=s_y[e][0], yx=s_y[e][1], yy=s_y[e][2], yz=s_y[e][3];
      float ss = s_up[src*128+c];
      const float* vp = v_up + src*384 + c*3;
      float vx=vp[0], vy=vp[1], vz=vp[2];
      float m1  = tp[ii][0]*ss*y0;
      float t1s = tp[ii][1]*ss;
      float m4  = tp[ii][3]*(vx*yx+vy*yy+vz*yz)*0.5773502691896258f;
      float t2y = tp[ii][2]*y0;
      uint4 pk;
      pk.x = bfp(m1,      m4);
      pk.y = bfp(t1s*yx,  t1s*yy);
      pk.z = bfp(t1s*yz,  t2y*vx);
      pk.w = bfp(t2y*vy,  t2y*vz);
      mjit[e*128 + c] = pk;
    }
  }
  __syncthreads();

  // ---- P3: g1 = mji @ W_se1p, silu. thread=(j<32, edge es<16) ----
  {
    const int j = t & 31, es = t >> 5;
    float g = 0.f;
    const float* wb = wse1p + j;
    for (int cc=0; cc<128; cc++){
      uint4 m = mjit[es*128+cc];
      const float* wp = wb + cc*256;
      g += bflo(m.x)*wp[0];   g += bfhi(m.x)*wp[32];
      g += bflo(m.y)*wp[64];  g += bfhi(m.y)*wp[96];
      g += bflo(m.z)*wp[128]; g += bfhi(m.z)*wp[160];
      g += bflo(m.w)*wp[192]; g += bfhi(m.w)*wp[224];
    }
    sg1[es*32+j] = siluf(g);
  }
  __syncthreads();

  // ---- P4: gate2 + sigmoid + multiply + atomic scatter ----
  {
    const unsigned short* mjus = (const unsigned short*)mjit;
    #pragma unroll
    for (int pass=0; pass<2; pass++){
      int dp = t + 512*pass;
      float wv[32];
      #pragma unroll
      for (int j=0;j<32;j++) wv[j] = wse2p[j*1024+dp];
      for (int e=0;e<16;e++){
        float a=0.f;
        #pragma unroll
        for (int j=0;j<32;j++) a += sg1[e*32+j]*wv[j];
        float gate = sigf(a);
        float val = __uint_as_float(((unsigned int)mjus[e*1024+dp])<<16) * gate;
        unsafeAtomicAdd(acc + (size_t)s_dst[e]*1024 + dp, val);
      }
    }
  }
}

// ---------------- final node kernel: lin + skip einsum ----------------
__global__ __launch_bounds__(512) void node_out_kernel(
    const float* __restrict__ acc, const float* __restrict__ na,
    const float* __restrict__ Wl0, const float* __restrict__ Wl1,
    const float* __restrict__ Wsk0, const float* __restrict__ Wsk1,
    float* __restrict__ out)
{
  __shared__ float sacc[4*1024];
  __shared__ float smid_s[4][128];
  __shared__ float smid_v[4][128][3];
  __shared__ float sattr[4][10];
  const int t = threadIdx.x;
  const int n0 = blockIdx.x*4;
  for (int i=t;i<4096;i+=512) sacc[i] = acc[(size_t)n0*1024 + i];
  if (t < 40) sattr[t/10][t%10] = na[n0*10 + t];
  __syncthreads();
  const int v2 = t & 127, ns = t >> 7;
  const float* ac = sacc + ns*1024;
  // lin (W_lin0/W_lin1, f=1/16) then /AVG_NEIGH(16) => 1/256
  float s_a=0.f, va0=0.f, va1=0.f, va2=0.f;
  for (int u=0;u<128;u++){
    const float* a8 = ac + u*8;
    float w0  = Wl0[u*128+v2];
    float w1  = Wl1[u*128+v2];
    float w0b = Wl0[(128+u)*128+v2];
    float w1b = Wl1[(128+u)*128+v2];
    s_a += a8[0]*w0;  s_a += a8[1]*w0b;
    va0 += a8[2]*w1;  va1 += a8[3]*w1;  va2 += a8[4]*w1;
    va0 += a8[5]*w1b; va1 += a8[6]*w1b; va2 += a8[7]*w1b;
  }
  const float fl = 0.00390625f;
  smid_s[ns][v2] = s_a*fl;
  smid_v[ns][v2][0]=va0*fl; smid_v[ns][v2][1]=va1*fl; smid_v[ns][v2][2]=va2*fl;
  __syncthreads();
  // skip: out[v2] = sum_{u,w} mid[u] * attr[w] * Wsk[u][w][v2] * (1/sqrt(1280))
  float so=0.f,o0=0.f,o1=0.f,o2=0.f;
  for (int u=0;u<128;u++){
    float sv = smid_s[ns][u];
    float vx = smid_v[ns][u][0], vy = smid_v[ns][u][1], vz = smid_v[ns][u][2];
    const float* w0p = Wsk0 + u*1280 + v2;
    const float* w1p = Wsk1 + u*1280 + v2;
    #pragma unroll
    for (int w=0;w<10;w++){
      float aw = sattr[ns][w];
      float W0v = w0p[w*128];
      float W1v = w1p[w*128];
      so += W0v*(sv*aw);
      o0 += W1v*(vx*aw); o1 += W1v*(vy*aw); o2 += W1v*(vz*aw);
    }
  }
  const float fsk = 0.02795084971874737f;  // 1/sqrt(1280)
  float4 o; o.x = so*fsk; o.y = o0*fsk; o.z = o1*fsk; o.w = o2*fsk;
  *(float4*)(out + (size_t)(n0+ns)*512 + v2*4) = o;
}

extern "C" void kernel_launch(void* const* d_in, const int* in_sizes, int n_in,
                              void* d_out, int out_size, void* d_ws, size_t ws_size,
                              hipStream_t stream) {
  const float* node_attrs = (const float*)d_in[0];
  const float* node_feats = (const float*)d_in[1];
  const float* edge_attrs = (const float*)d_in[2];
  const float* edge_feats = (const float*)d_in[3];
  const int*   edge_index = (const int*)d_in[4];
  const float* W_up0 = (const float*)d_in[5];
  const float* W_up1 = (const float*)d_in[6];
  const float* Wr1   = (const float*)d_in[7];
  const float* Wr2   = (const float*)d_in[8];
  const float* Wr3   = (const float*)d_in[9];
  const float* Wr4   = (const float*)d_in[10];
  const float* W_se1 = (const float*)d_in[11];
  const float* W_se2 = (const float*)d_in[12];
  const float* W_lin0= (const float*)d_in[13];
  const float* W_lin1= (const float*)d_in[14];
  const float* W_sk0 = (const float*)d_in[15];
  const float* W_sk1 = (const float*)d_in[16];

  float* ws   = (float*)d_ws;
  float* acc  = ws;                      // N*1024 = 10,240,000
  float* s_up = ws + 10240000;           // N*128  =  1,280,000
  float* v_up = s_up + 1280000;          // N*384  =  3,840,000
  float* wr4p = v_up + 3840000;          // 32768
  float* wse1p= wr4p + 32768;            // 32768
  float* wse2p= wse1p + 32768;           // 32768

  hipMemsetAsync(acc, 0, (size_t)10240000*4, stream);
  pack_weights<<<128, 256, 0, stream>>>(Wr4, W_se1, W_se2, wr4p, wse1p, wse2p);
  node_up_kernel<<<N_NODES, 128, 0, stream>>>(node_feats, W_up0, W_up1, s_up, v_up);
  edge_kernel<<<N_EDGES/16, 512, 0, stream>>>(edge_feats, edge_attrs, edge_index,
      Wr1, Wr2, Wr3, wr4p, wse1p, wse2p, s_up, v_up, acc);
  node_out_kernel<<<N_NODES/4, 512, 0, stream>>>(acc, node_attrs,
      W_lin0, W_lin1, W_sk0, W_sk1, (float*)d_out);
}

// Round 6
// 1365.062 us; speedup vs baseline: 1.2564x; 1.2564x over previous
//
#include <hip/hip_runtime.h>
#include <hip/hip_bf16.h>

#define N_NODES 10000
#define N_EDGES 160000

typedef __bf16 bf16x8 __attribute__((ext_vector_type(8)));
typedef float  f32x4  __attribute__((ext_vector_type(4)));

__device__ __forceinline__ float sigf(float x){ return 1.0f/(1.0f+__expf(-x)); }
__device__ __forceinline__ float siluf(float x){ return x*sigf(x); }

__device__ __forceinline__ unsigned int f2bfbits(float f){
  unsigned int u = __float_as_uint(f);
  return (u + 0x7fffu + ((u>>16)&1u)) >> 16;
}
__device__ __forceinline__ unsigned int bfp(float a, float b){
  return f2bfbits(a) | (f2bfbits(b)<<16);
}

// d' (permuted message dim) -> d (reference mji dim). d' = c*8 + slot.
__device__ __forceinline__ int dmap(int dp){
  int c = dp>>3, slot = dp&7;
  if (slot==0) return c;
  if (slot==1) return 128+c;
  if (slot<5)  return 256+3*c+(slot-2);
  return 640+3*c+(slot-5);
}

// ---------------- pack weights ----------------
// wr4p (f32, R1 layout): wr4p[k*512 + c*4 + q] = Wr4[k][q*128+c] * (1/8)
// wse1pk (bf16 B-fragments, TRIPLE split hi/mid/lo at +0/+32768/+65536):
//    [nt:2][kb:32][lane:64][j:8], B = W_se1[dmap(kb*32 + (l>>4)*8 + j)][nt*16 + (l&15)]
// wse2p (f32, R1 layout): wse2p[j*1024 + dp] = W_se2[j][dmap(dp)]
__global__ void pack_weights(const float* __restrict__ Wr4,
                             const float* __restrict__ Wse1,
                             const float* __restrict__ Wse2,
                             float* __restrict__ wr4p,
                             unsigned short* __restrict__ wse1pk,
                             float* __restrict__ wse2p)
{
  int t = blockIdx.x*256 + threadIdx.x;   // 0..32767
  { // wr4p f32 (exact R1 indexing)
    int k = t >> 9; int rem = t & 511; int c = rem >> 2; int q = rem & 3;
    wr4p[t] = Wr4[k*512 + q*128 + c] * 0.125f;
  }
  { // wse1pk triple split
    int j = t&7, l = (t>>3)&63;
    int lg = l>>4, lm = l&15;
    int kb = (t>>9)&31; int nt = t>>14;
    int d = dmap(kb*32 + lg*8 + j);
    int col = nt*16 + lm;
    float v = Wse1[d*32+col];
    unsigned int hb = f2bfbits(v);
    float hf = __uint_as_float(hb<<16);
    float r1 = v - hf;
    unsigned int mb = f2bfbits(r1);
    float mf = __uint_as_float(mb<<16);
    unsigned int lb = f2bfbits(r1 - mf);
    wse1pk[t]        = (unsigned short)hb;
    wse1pk[t+32768]  = (unsigned short)mb;
    wse1pk[t+65536]  = (unsigned short)lb;
  }
  { // wse2p f32 (exact R1 indexing)
    int dp = t >> 5; int j = t & 31;
    int d = dmap(dp);
    wse2p[j*1024 + dp] = Wse2[j*1024 + d];
  }
}

// ---------------- node up-projection ----------------
__global__ __launch_bounds__(128) void node_up_kernel(
    const float* __restrict__ nf, const float* __restrict__ W0, const float* __restrict__ W1,
    float* __restrict__ s_up, float* __restrict__ v_up)
{
  int n = blockIdx.x; int c = threadIdx.x;
  __shared__ float row[512];
  #pragma unroll
  for (int i=0;i<4;i++) row[c + 128*i] = nf[n*512 + c + 128*i];
  __syncthreads();
  float as=0.f, a0=0.f, a1=0.f, a2=0.f;
  for (int u=0;u<128;u++){
    float w0 = W0[u*128+c], w1 = W1[u*128+c];
    as += row[u]*w0;
    a0 += row[128+u*3+0]*w1;
    a1 += row[128+u*3+1]*w1;
    a2 += row[128+u*3+2]*w1;
  }
  const float f = 0.08838834764831845f;   // 1/sqrt(128)
  s_up[n*128+c] = as*f;
  v_up[n*384 + c*3+0] = a0*f;
  v_up[n*384 + c*3+1] = a1*f;
  v_up[n*384 + c*3+2] = a2*f;
}

// ---------------- fused edge kernel: P1/P2/P4 = R1 f32, P3 = exact-operand MFMA ----------------
// LDS layout (bytes):
//  [0,16384)      : hA(16x64 f32)@0, hB@4096 during P1/P2; partial[8][16][32] f32 during P3
//  [16384,49152)  : mji bf16 [16 e][1024 d'], XOR-swizzled: byte ^= (e&7)<<4
//  [49152,51200)  : sg1 f32 [16][32]
//  [51200,...)    : s_src[16], s_dst[16], s_y[16][4]
#define OFF_MJI  16384
#define OFF_SG1  49152
#define OFF_SRC  51200
#define OFF_DST  51264
#define OFF_Y    51328

__global__ __launch_bounds__(512, 4) void edge_kernel(
    const float* __restrict__ ef, const float* __restrict__ ea, const int* __restrict__ ei,
    const float* __restrict__ Wr1, const float* __restrict__ Wr2, const float* __restrict__ Wr3,
    const float* __restrict__ wr4p, const unsigned short* __restrict__ wse1pk,
    const float* __restrict__ wse2p,
    const float* __restrict__ s_up, const float* __restrict__ v_up, float* __restrict__ accg)
{
  __shared__ __align__(16) char smem[51584];
  float* hA = (float*)smem;
  float* hB = (float*)(smem + 4096);
  float* partial = (float*)smem;
  float* sg1  = (float*)(smem + OFF_SG1);
  int*   s_src = (int*)(smem + OFF_SRC);
  int*   s_dst = (int*)(smem + OFF_DST);
  float* s_y   = (float*)(smem + OFF_Y);

  const int t = threadIdx.x;
  const int e0 = blockIdx.x * 16;
  const int l = t & 63, w = t >> 6;        // lane, wave
  const int lg = l >> 4, lm = l & 15;

  if (t < 16){ s_src[t] = ei[e0+t]; s_dst[t] = ei[N_EDGES + e0 + t]; }
  else if (t >= 64 && t < 128){ int q=t-64; s_y[(q>>2)*4 + (q&3)] = ea[(e0+(q>>2))*4 + (q&3)]; }

  // ---- P1 (R1): MLP 8->64->64->64 (+silu); h3 -> hA f32 ----
  {
    const int i = t & 63, eh = t >> 6;
    float r0, r1;
    { float a0=0.f,a1=0.f;
      #pragma unroll
      for (int k=0;k<8;k++){ float wv = Wr1[k*64+i];
        a0 += ef[(e0+eh)*8+k]*wv; a1 += ef[(e0+eh+8)*8+k]*wv; }
      r0 = siluf(a0*0.35355339059327373f); r1 = siluf(a1*0.35355339059327373f);
    }
    hA[eh*64+i]=r0; hA[(eh+8)*64+i]=r1;
    __syncthreads();
    { float a0=0.f,a1=0.f;
      for (int k=0;k<64;k++){ float wv = Wr2[k*64+i];
        a0 += hA[eh*64+k]*wv; a1 += hA[(eh+8)*64+k]*wv; }
      r0=siluf(a0*0.125f); r1=siluf(a1*0.125f);
    }
    hB[eh*64+i]=r0; hB[(eh+8)*64+i]=r1;
    __syncthreads();
    { float a0=0.f,a1=0.f;
      for (int k=0;k<64;k++){ float wv = Wr3[k*64+i];
        a0 += hB[eh*64+k]*wv; a1 += hB[(eh+8)*64+k]*wv; }
      r0=siluf(a0*0.125f); r1=siluf(a1*0.125f);
    }
    hA[eh*64+i]=r0; hA[(eh+8)*64+i]=r1;   // h3 -> hA (nobody reads hA after 2nd sync)
  }
  __syncthreads();

  // ---- P2 (R1 f32): tpw + gather + messages -> mji bf16 (swizzled store) ----
  {
    const int c = t & 127, es = t >> 7;
    float tp[4][4];
    #pragma unroll
    for (int ii=0;ii<4;ii++){ tp[ii][0]=0.f; tp[ii][1]=0.f; tp[ii][2]=0.f; tp[ii][3]=0.f; }
    for (int k=0;k<64;k++){
      float4 wv = *(const float4*)(wr4p + k*512 + c*4);
      #pragma unroll
      for (int ii=0;ii<4;ii++){
        float h = hA[(es+4*ii)*64+k];
        tp[ii][0] += h*wv.x; tp[ii][1] += h*wv.y; tp[ii][2] += h*wv.z; tp[ii][3] += h*wv.w;
      }
    }
    #pragma unroll
    for (int ii=0;ii<4;ii++){
      int e = es + 4*ii;
      int src = s_src[e];
      float y0=s_y[e*4+0], yx=s_y[e*4+1], yy=s_y[e*4+2], yz=s_y[e*4+3];
      float ss = s_up[src*128+c];
      const float* vp = v_up + src*384 + c*3;
      float vx=vp[0], vy=vp[1], vz=vp[2];
      float m1  = tp[ii][0]*ss*y0;
      float t1s = tp[ii][1]*ss;
      float t2y = tp[ii][2]*y0;
      float m4  = tp[ii][3]*(vx*yx+vy*yy+vz*yz)*0.5773502691896258f;
      uint4 pk;
      pk.x = bfp(m1,      m4);
      pk.y = bfp(t1s*yx,  t1s*yy);
      pk.z = bfp(t1s*yz,  t2y*vx);
      pk.w = bfp(t2y*vy,  t2y*vz);
      *(uint4*)(smem + OFF_MJI + ((e*2048 + c*16) ^ ((e&7)<<4))) = pk;
    }
  }
  __syncthreads();

  // ---- P3 (MFMA, exact operands): gate1 = mji[16x1024] @ Wse1[1024x32] ----
  // A = bf16 mji (bit-identical to R1's f32-loop input); B = triple-split (~f32 exact).
  {
    f32x4 acc0 = {0.f,0.f,0.f,0.f}, acc1 = {0.f,0.f,0.f,0.f};
    #pragma unroll
    for (int ik=0; ik<4; ik++){
      int kb = w*4 + ik;
      bf16x8 a = *(const bf16x8*)(smem + OFF_MJI + ((lm*2048 + kb*64 + lg*16) ^ ((lm&7)<<4)));
      #pragma unroll
      for (int p=0;p<3;p++){
        bf16x8 b0 = *(const bf16x8*)(wse1pk + p*32768 + (0*32+kb)*512 + l*8);
        bf16x8 b1 = *(const bf16x8*)(wse1pk + p*32768 + (1*32+kb)*512 + l*8);
        acc0 = __builtin_amdgcn_mfma_f32_16x16x32_bf16(a,b0,acc0,0,0,0);
        acc1 = __builtin_amdgcn_mfma_f32_16x16x32_bf16(a,b1,acc1,0,0,0);
      }
    }
    #pragma unroll
    for (int r=0;r<4;r++){
      int row = lg*4 + r;
      partial[(w*16+row)*32 + lm     ] = acc0[r];
      partial[(w*16+row)*32 + 16+lm  ] = acc1[r];
    }
  }
  __syncthreads();
  { // reduce 8 partials + silu -> sg1 f32
    int e = t>>5, jj = t&31;
    float s = 0.f;
    #pragma unroll
    for (int w8=0; w8<8; w8++) s += partial[(w8*16+e)*32 + jj];
    sg1[e*32+jj] = siluf(s);
  }
  __syncthreads();

  // ---- P4 (R1 f32): gate2 + sigmoid + multiply + atomic scatter (swizzled mji read) ----
  {
    #pragma unroll
    for (int pass=0; pass<2; pass++){
      int dp = t + 512*pass;
      float wv[32];
      #pragma unroll
      for (int j=0;j<32;j++) wv[j] = wse2p[j*1024+dp];
      for (int e=0;e<16;e++){
        float a=0.f;
        #pragma unroll
        for (int j=0;j<32;j++) a += sg1[e*32+j]*wv[j];
        float gate = sigf(a);
        unsigned short mv = *(const unsigned short*)(smem + OFF_MJI + ((e*2048 + dp*2) ^ ((e&7)<<4)));
        float val = __uint_as_float(((unsigned int)mv)<<16) * gate;
        unsafeAtomicAdd(accg + (size_t)s_dst[e]*1024 + dp, val);
      }
    }
  }
}

// ---------------- final node kernel: lin + skip einsum ----------------
__global__ __launch_bounds__(512) void node_out_kernel(
    const float* __restrict__ acc, const float* __restrict__ na,
    const float* __restrict__ Wl0, const float* __restrict__ Wl1,
    const float* __restrict__ Wsk0, const float* __restrict__ Wsk1,
    float* __restrict__ out)
{
  __shared__ float sacc[4*1024];
  __shared__ float smid_s[4][128];
  __shared__ float smid_v[4][128][3];
  __shared__ float sattr[4][10];
  const int t = threadIdx.x;
  const int n0 = blockIdx.x*4;
  for (int i=t;i<4096;i+=512) sacc[i] = acc[(size_t)n0*1024 + i];
  if (t < 40) sattr[t/10][t%10] = na[n0*10 + t];
  __syncthreads();
  const int v2 = t & 127, ns = t >> 7;
  const float* ac = sacc + ns*1024;
  float s_a=0.f, va0=0.f, va1=0.f, va2=0.f;
  for (int u=0;u<128;u++){
    const float* a8 = ac + u*8;
    float w0  = Wl0[u*128+v2];
    float w1  = Wl1[u*128+v2];
    float w0b = Wl0[(128+u)*128+v2];
    float w1b = Wl1[(128+u)*128+v2];
    s_a += a8[0]*w0;  s_a += a8[1]*w0b;
    va0 += a8[2]*w1;  va1 += a8[3]*w1;  va2 += a8[4]*w1;
    va0 += a8[5]*w1b; va1 += a8[6]*w1b; va2 += a8[7]*w1b;
  }
  const float fl = 0.00390625f;
  smid_s[ns][v2] = s_a*fl;
  smid_v[ns][v2][0]=va0*fl; smid_v[ns][v2][1]=va1*fl; smid_v[ns][v2][2]=va2*fl;
  __syncthreads();
  float so=0.f,o0=0.f,o1=0.f,o2=0.f;
  for (int u=0;u<128;u++){
    float sv = smid_s[ns][u];
    float vx = smid_v[ns][u][0], vy = smid_v[ns][u][1], vz = smid_v[ns][u][2];
    const float* w0p = Wsk0 + u*1280 + v2;
    const float* w1p = Wsk1 + u*1280 + v2;
    #pragma unroll
    for (int wq=0;wq<10;wq++){
      float aw = sattr[ns][wq];
      float W0v = w0p[wq*128];
      float W1v = w1p[wq*128];
      so += W0v*(sv*aw);
      o0 += W1v*(vx*aw); o1 += W1v*(vy*aw); o2 += W1v*(vz*aw);
    }
  }
  const float fsk = 0.02795084971874737f;  // 1/sqrt(1280)
  float4 o; o.x = so*fsk; o.y = o0*fsk; o.z = o1*fsk; o.w = o2*fsk;
  *(float4*)(out + (size_t)(n0+ns)*512 + v2*4) = o;
}

extern "C" void kernel_launch(void* const* d_in, const int* in_sizes, int n_in,
                              void* d_out, int out_size, void* d_ws, size_t ws_size,
                              hipStream_t stream) {
  const float* node_attrs = (const float*)d_in[0];
  const float* node_feats = (const float*)d_in[1];
  const float* edge_attrs = (const float*)d_in[2];
  const float* edge_feats = (const float*)d_in[3];
  const int*   edge_index = (const int*)d_in[4];
  const float* W_up0 = (const float*)d_in[5];
  const float* W_up1 = (const float*)d_in[6];
  const float* Wr1   = (const float*)d_in[7];
  const float* Wr2   = (const float*)d_in[8];
  const float* Wr3   = (const float*)d_in[9];
  const float* Wr4   = (const float*)d_in[10];
  const float* W_se1 = (const float*)d_in[11];
  const float* W_se2 = (const float*)d_in[12];
  const float* W_lin0= (const float*)d_in[13];
  const float* W_lin1= (const float*)d_in[14];
  const float* W_sk0 = (const float*)d_in[15];
  const float* W_sk1 = (const float*)d_in[16];

  float* ws   = (float*)d_ws;
  float* accg = ws;                      // N*1024 = 10,240,000 f32
  float* s_up = ws + 10240000;           // N*128
  float* v_up = s_up + 1280000;          // N*384
  float* wr4p = v_up + 3840000;          // 32768 f32
  unsigned short* wse1pk = (unsigned short*)(wr4p + 32768);   // 98304 ushort (hi+mid+lo)
  float* wse2p = (float*)(wse1pk + 98304);                    // 32768 f32

  hipMemsetAsync(accg, 0, (size_t)10240000*4, stream);
  pack_weights<<<128, 256, 0, stream>>>(Wr4, W_se1, W_se2, wr4p, wse1pk, wse2p);
  node_up_kernel<<<N_NODES, 128, 0, stream>>>(node_feats, W_up0, W_up1, s_up, v_up);
  edge_kernel<<<N_EDGES/16, 512, 0, stream>>>(edge_feats, edge_attrs, edge_index,
      Wr1, Wr2, Wr3, wr4p, wse1pk, wse2p, s_up, v_up, accg);
  node_out_kernel<<<N_NODES/4, 512, 0, stream>>>(accg, node_attrs,
      W_lin0, W_lin1, W_sk0, W_sk1, (float*)d_out);
}